// Round 6
// baseline (363.499 us; speedup 1.0000x reference)
//
#include <hip/hip_runtime.h>
#include <hip/hip_bf16.h>

typedef __attribute__((ext_vector_type(8))) short bfrag;   // 8 x bf16 (4 VGPRs)
typedef __attribute__((ext_vector_type(4))) float ffrag;   // 4 x f32 acc

#define NB 1024
#define NT 256

// -log2(e), -2*log2(e): folded into weights so S2 needs no per-activation mul.
#define KSIG -1.44269504f
#define KTAN -2.88539008f

static __device__ __forceinline__ float fast_rcp(float x) { return __builtin_amdgcn_rcpf(x); }
// unscaled (logit path only)
static __device__ __forceinline__ float sigm(float x) {
  return fast_rcp(1.f + __builtin_amdgcn_exp2f(-1.44269504f * x));
}
// pre-scaled args (weights already multiplied by KSIG/KTAN)
static __device__ __forceinline__ float sigm_pre(float s) {
  return fast_rcp(1.f + __builtin_amdgcn_exp2f(s));
}
static __device__ __forceinline__ float tanh_pre(float s) {
  return __builtin_fmaf(2.f, fast_rcp(1.f + __builtin_amdgcn_exp2f(s)), -1.f);
}
static __device__ __forceinline__ float tanh_f(float x) {
  return __builtin_fmaf(2.f, fast_rcp(1.f + __builtin_amdgcn_exp2f(-2.88539008f * x)), -1.f);
}
static __device__ __forceinline__ float bf2f(__hip_bfloat16 v) { return __bfloat162float(v); }
static __device__ __forceinline__ short f2bs(float f) {
  __hip_bfloat16 h = __float2bfloat16(f);
  return *reinterpret_cast<short*>(&h);
}
// LDS-only barrier: skip the vmcnt(0) drain __syncthreads would force.
static __device__ __forceinline__ void barrier_lgkm() {
  asm volatile("s_waitcnt lgkmcnt(0)\n\ts_barrier" ::: "memory");
}

// ---------------------------------------------------------------------------
// R17 = R12 (VERIFIED 352us base: 64 blocks x 16 rows, staging-free gathers,
// pre-scaled weights, one LDS-only barrier/step) + three local deltas:
//  (a) out_b slot-buffer/flush DELETED -> wave 7 direct float2 global stores
//      (fire-and-forget; barrier_lgkm doesn't drain vmcnt).
//  (b) t+1 input gathers (id + axA/axB ds_reads) hoisted to iteration top so
//      their lgkm latency overlaps the h-MFMA chain.
//  (c) s_setprio(1/0) around the h-MFMA cluster.
// Grid-256/4-row line ABANDONED after R13-R16 (4 failures, signature =
// logit column ~0/unwritten; cause not statically findable).
// ---------------------------------------------------------------------------
__global__ __launch_bounds__(512, 2) void gru_kernel(
    const float* __restrict__ x,     // [B,64]
    const int* __restrict__ a_ids,   // [B,T]
    const int* __restrict__ t_ids,   // [B,T]
    const float* __restrict__ y,     // [B,T]
    const float* __restrict__ eps,   // [B,T,16]
    const float* __restrict__ Wx,    // [64,64]
    const float* __restrict__ bx,    // [64]
    const float* __restrict__ Ea,    // [100,32]
    const float* __restrict__ Et,    // [4,16]
    const float* __restrict__ Wih,   // [384,129]
    const float* __restrict__ Whh,   // [384,128]
    const float* __restrict__ bih,   // [384]
    const float* __restrict__ bhh,   // [384]
    const float* __restrict__ W0,    // [128,80]
    const float* __restrict__ b0g,   // [128]
    const float* __restrict__ Wy,    // [1,128]
    const float* __restrict__ by,    // [1]
    float* __restrict__ out)         // [B,T,2]
{
  // ---- persistent LDS ----
  __shared__ __align__(16) __hip_bfloat16 h_bf[2][16][136];  // h mirror (h_bf[1] = xdyn in prologue)
  __shared__ __align__(16) __hip_bfloat16 Ea_s[100][40];     // padded rows (data in cols 0..31)
  __shared__ __align__(16) __hip_bfloat16 Et_s[4][16];
  __shared__ float prevy_s[2][16];
  __shared__ float bsum_r[128], bsum_z[128], bihn_s[128], bhhn_s[128];  // pre-scaled
  __shared__ float wprev_s[384];                                        // pre-scaled
  // ---- unioned region (38912 B) ----
  // persistent: id_s[256][16]u16 @0 | eps_ch[2][16][16][24]bf16 @8192
  //             y_ch[2][16][16]f32 @32768
  // prologue:   Wxb[64][64]bf16 @0 | W0b[128][80]bf16 @8192 | x_s[16][65]f32 @28672
  //             eps0s[16][17]f32 @32832 | xe_s[16][65]f32 @33920 | h0f[16][128]f32 @0
  __shared__ __align__(16) char uni[38912];
  unsigned short* id_s    = (unsigned short*)(uni);
  __hip_bfloat16* eps_ch  = (__hip_bfloat16*)(uni + 8192);
  float*          y_ch    = (float*)(uni + 32768);
  __hip_bfloat16* Wxb     = (__hip_bfloat16*)(uni);
  __hip_bfloat16* W0b     = (__hip_bfloat16*)(uni + 8192);
  float*          x_s     = (float*)(uni + 28672);
  float*          eps0s   = (float*)(uni + 32832);
  float*          xe_s    = (float*)(uni + 33920);
  float*          h0f     = (float*)(uni);

  const int tid = threadIdx.x;
  const int w = tid >> 6, l = tid & 63;
  const int lmod = l & 15, ldiv = l >> 4;
  const int i_own = 16 * w + lmod;
  const int b0 = blockIdx.x * 16;

  // ================= PROLOGUE =================
  if (tid < 128) {
    bsum_r[tid] = KSIG * (bih[tid] + bhh[tid]);
    bsum_z[tid] = KSIG * (bih[128 + tid] + bhh[128 + tid]);
    bihn_s[tid] = KTAN * bih[256 + tid];
    bhhn_s[tid] = KTAN * bhh[256 + tid];
  }
  if (tid < 384) wprev_s[tid] = ((tid < 256) ? KSIG : KTAN) * Wih[tid * 129 + 128];
  for (int j = tid; j < 3200; j += 512) {
    int r = j >> 5, c = j & 31;
    Ea_s[r][c] = __float2bfloat16(Ea[j]);
  }
  if (tid < 64) ((__hip_bfloat16*)Et_s)[tid] = __float2bfloat16(Et[tid]);
  for (int j = tid; j < 4096; j += 512)  Wxb[j] = __float2bfloat16(Wx[j]);
  for (int j = tid; j < 10240; j += 512) W0b[j] = __float2bfloat16(W0[j]);
  for (int j = tid; j < 1024; j += 512) {
    int r = j >> 6, c = j & 63;
    x_s[r * 65 + c] = x[(b0 + r) * 64 + c];
  }
  if (tid < 256) {
    int r = tid >> 4, c = tid & 15;
    eps0s[r * 17 + c] = eps[((b0 + r) * NT) * 16 + c];
  }
  const float by_f = by[0];

  // persistent B-frags: wave w owns gate-cols i_own of r/z/n. Pre-scaled.
  bfrag Bh[3][4], Bi[3][2];
  #pragma unroll
  for (int g = 0; g < 3; g++) {
    const float sg = (g < 2) ? KSIG : KTAN;
    int n = (g * 8 + w) * 16 + lmod;
    #pragma unroll
    for (int kc = 0; kc < 4; kc++) {
      int k = kc * 32 + ldiv * 8;
      const float* wh = Whh + n * 128 + k;
      float4 h0v = *reinterpret_cast<const float4*>(wh);
      float4 h1v = *reinterpret_cast<const float4*>(wh + 4);
      bfrag th = {f2bs(sg * h0v.x), f2bs(sg * h0v.y), f2bs(sg * h0v.z), f2bs(sg * h0v.w),
                  f2bs(sg * h1v.x), f2bs(sg * h1v.y), f2bs(sg * h1v.z), f2bs(sg * h1v.w)};
      Bh[g][kc] = th;
    }
    #pragma unroll
    for (int kc = 0; kc < 2; kc++) {
      bfrag ti;
      #pragma unroll
      for (int j = 0; j < 8; j++) {
        int dk = kc * 32 + ldiv * 8 + j;
        int col = dk < 48 ? dk : dk + 64;
        ti[j] = f2bs(sg * Wih[n * 129 + col]);
      }
      Bi[g][kc] = ti;
    }
  }
  // logit B-tile for wave 7: col 0 = Wy, other cols 0 (UNscaled)
  bfrag Bl[4];
  if (w == 7) {
    #pragma unroll
    for (int kc = 0; kc < 4; kc++) {
      bfrag bt;
      #pragma unroll
      for (int j = 0; j < 8; j++)
        bt[j] = (lmod == 0) ? f2bs(Wy[kc * 32 + ldiv * 8 + j]) : (short)0;
      Bl[kc] = bt;
    }
  }
  __syncthreads();  // B1: x_s, Wxb, tables ready

  // ph1: xenc = x@Wx.T + bx -> xe_s (f32) + xdyn bf16 (in h_bf[1])
  for (int j = tid; j < 1024; j += 512) {
    int r = j & 15, i = j >> 4;
    float acc = bx[i];
    #pragma unroll 8
    for (int k = 0; k < 64; k++) acc += x_s[r * 65 + k] * bf2f(Wxb[i * 64 + k]);
    xe_s[r * 65 + i] = acc;
    h_bf[1][r][i] = __float2bfloat16(acc);
  }
  __syncthreads();  // B2: xe_s + xdyn ready; Wxb dead

  // ph2: h0 = tanh([xenc,eps0]@W0.T + b0) -> h0f (overwrites Wxb region)
  for (int j = tid; j < 2048; j += 512) {
    int r = j & 15, o = j >> 4;
    float acc = b0g[o];
    #pragma unroll 8
    for (int k = 0; k < 64; k++) acc += xe_s[r * 65 + k] * bf2f(W0b[o * 80 + k]);
    #pragma unroll
    for (int k = 0; k < 16; k++) acc += eps0s[r * 17 + k] * bf2f(W0b[o * 80 + 64 + k]);
    h0f[r * 128 + o] = tanh_f(acc);
  }

  // gxc = scaled( xenc @ Wih[:,48:112].T + per-gate biases )
  ffrag gxc[3];
  {
    ffrag z = {0.f, 0.f, 0.f, 0.f};
    gxc[0] = z; gxc[1] = z; gxc[2] = z;
    #pragma unroll
    for (int kc = 0; kc < 2; kc++) {
      bfrag axd = *reinterpret_cast<const bfrag*>(&h_bf[1][lmod][kc * 32 + ldiv * 8]);
      #pragma unroll
      for (int g = 0; g < 3; g++) {
        const float sg = (g < 2) ? KSIG : KTAN;
        int n = (g * 8 + w) * 16 + lmod;
        const float* wi = Wih + n * 129 + 48 + kc * 32 + ldiv * 8;
        bfrag bt;
        #pragma unroll
        for (int j = 0; j < 8; j++) bt[j] = f2bs(sg * wi[j]);
        gxc[g] = __builtin_amdgcn_mfma_f32_16x16x32_bf16(axd, bt, gxc[g], 0, 0, 0);
      }
    }
    float brf = bsum_r[i_own], bzf = bsum_z[i_own], bn1 = bihn_s[i_own];
    #pragma unroll
    for (int q = 0; q < 4; q++) {
      gxc[0][q] += brf;
      gxc[1][q] += bzf;
      gxc[2][q] += bn1;
    }
  }
  __syncthreads();  // B3: h0f complete; gxc done

  // h init: fp32 regs + bf16 mirror in h_bf[0]
  float h_reg[4];
  #pragma unroll
  for (int q = 0; q < 4; q++) {
    int row = ldiv * 4 + q;
    float hv = h0f[row * 128 + i_own];
    h_reg[q] = hv;
    h_bf[0][row][i_own] = __float2bfloat16(hv);
  }
  __syncthreads();  // B4: h0f dead; uni becomes persistent

  // ids (packed, [t][row]) + chunk 0 of eps/y
  for (int j = tid; j < 4096; j += 512) {
    int r = j >> 8, t = j & 255;
    unsigned short v = (unsigned short)(a_ids[(b0 + r) * NT + t] |
                                        (t_ids[(b0 + r) * NT + t] << 8));
    id_s[t * 16 + r] = v;
  }
  {
    int r = tid >> 5, sub = tid & 31;
    const float* p = eps + ((b0 + r) * NT) * 16 + sub * 8;
    float4 eA = *reinterpret_cast<const float4*>(p);
    float4 eB = *reinterpret_cast<const float4*>(p + 4);
    int toff = sub >> 1, c8 = (sub & 1) * 8;
    bfrag e = {f2bs(eA.x), f2bs(eA.y), f2bs(eA.z), f2bs(eA.w),
               f2bs(eB.x), f2bs(eB.y), f2bs(eB.z), f2bs(eB.w)};
    *reinterpret_cast<bfrag*>(&eps_ch[(toff * 16 + r) * 24 + c8]) = e;
    if (tid < 64) {
      int r2 = tid >> 2, s2 = tid & 3;
      float4 yv = *reinterpret_cast<const float4*>(y + (b0 + r2) * NT + s2 * 4);
      *reinterpret_cast<float4*>(&y_ch[r2 * 16 + s2 * 4]) = yv;
    }
  }
  if (tid < 16) prevy_s[0][tid] = 0.f;
  // hoisted per-lane constants (pre-scaled)
  const float wpr = wprev_s[i_own], wpz = wprev_s[128 + i_own], wpn = wprev_s[256 + i_own];
  const float bn2 = bhhn_s[i_own];
  // hoisted per-lane address pieces for the direct dyn-input gather
  const char* const ea_base  = (const char*)Ea_s + ldiv * 16;
  const char* const et_base  = (const char*)Et_s + ldiv * 16;
  const char* const eps_base = (const char*)eps_ch + lmod * 48 + (ldiv - 2) * 16;
  __syncthreads();  // B5: id_s / eps_ch chunk0 / y_ch ready

  // input-gate MFMAs for t=0
  ffrag pa0 = gxc[0], pa1 = gxc[1], pa2 = gxc[2];
  {
    int id = id_s[lmod];
    int aid = id & 127, tv = id >> 8;
    bfrag axA = *reinterpret_cast<const bfrag*>(ea_base + aid * 80);
    const char* etp = et_base + tv * 32;
    const char* epp = eps_base;  // t=0: cbn=0, tm=0
    bfrag axB = *reinterpret_cast<const bfrag*>(ldiv < 2 ? etp : epp);
    pa0 = __builtin_amdgcn_mfma_f32_16x16x32_bf16(axA, Bi[0][0], pa0, 0, 0, 0);
    pa1 = __builtin_amdgcn_mfma_f32_16x16x32_bf16(axA, Bi[1][0], pa1, 0, 0, 0);
    pa2 = __builtin_amdgcn_mfma_f32_16x16x32_bf16(axA, Bi[2][0], pa2, 0, 0, 0);
    pa0 = __builtin_amdgcn_mfma_f32_16x16x32_bf16(axB, Bi[0][1], pa0, 0, 0, 0);
    pa1 = __builtin_amdgcn_mfma_f32_16x16x32_bf16(axB, Bi[1][1], pa1, 0, 0, 0);
    pa2 = __builtin_amdgcn_mfma_f32_16x16x32_bf16(axB, Bi[2][1], pa2, 0, 0, 0);
  }

  // ================= MAIN LOOP =================
  for (int t = 0; t < NT; t++) {
    const int buf = t & 1, nbuf = buf ^ 1;

    // issue next-chunk global loads (rare)
    const bool ck = ((t & 15) == 0) && (t + 16 < NT);
    float4 eA, eB, yv;
    const int cr = tid >> 5, csub = tid & 31;
    if (ck) {
      const float* p = eps + ((b0 + cr) * NT + t + 16) * 16 + csub * 8;
      eA = *reinterpret_cast<const float4*>(p);
      eB = *reinterpret_cast<const float4*>(p + 4);
      if (tid < 64) {
        int r2 = tid >> 2, s2 = tid & 3;
        yv = *reinterpret_cast<const float4*>(y + (b0 + r2) * NT + t + 16 + s2 * 4);
      }
    }

    // t+1 gather register-prefetch (LDS data written >=1 barrier ago) —
    // hoisted so its lgkm latency hides under the h-MFMA chain below.
    bfrag axA_n, axB_n;
    if (t + 1 < NT) {
      const int tn = t + 1;
      int id = id_s[tn * 16 + lmod];
      int aid = id & 127, tv = id >> 8;
      axA_n = *reinterpret_cast<const bfrag*>(ea_base + aid * 80);
      const char* etp = et_base + tv * 32;
      const int ebase2 = (((tn >> 4) & 1) * 16 + (tn & 15)) * 16;
      const char* epp = eps_base + ebase2 * 48;
      axB_n = *reinterpret_cast<const bfrag*>(ldiv < 2 ? etp : epp);
    }

    // h-MFMAs: the only barrier-dependent work
    ffrag anh, agl;
    #pragma unroll
    for (int q = 0; q < 4; q++) anh[q] = bn2;
    if (w == 7) {
      #pragma unroll
      for (int q = 0; q < 4; q++) agl[q] = by_f;
    }
    __builtin_amdgcn_s_setprio(1);
    #pragma unroll
    for (int kc = 0; kc < 4; kc++) {
      bfrag ah = *reinterpret_cast<const bfrag*>(&h_bf[buf][lmod][kc * 32 + ldiv * 8]);
      pa0 = __builtin_amdgcn_mfma_f32_16x16x32_bf16(ah, Bh[0][kc], pa0, 0, 0, 0);
      pa1 = __builtin_amdgcn_mfma_f32_16x16x32_bf16(ah, Bh[1][kc], pa1, 0, 0, 0);
      anh = __builtin_amdgcn_mfma_f32_16x16x32_bf16(ah, Bh[2][kc], anh, 0, 0, 0);
      if (w == 7)
        agl = __builtin_amdgcn_mfma_f32_16x16x32_bf16(ah, Bl[kc], agl, 0, 0, 0);
    }
    __builtin_amdgcn_s_setprio(0);

    // prevy for t+1 (wave 6)
    if (tid >= 384 && tid < 400) {
      int r = tid - 384;
      prevy_s[nbuf][r] = y_ch[((t >> 4) & 1) * 256 + r * 16 + (t & 15)];
    }

    // wave 7: logit/prob for step t-1 -> DIRECT global float2 stores
    if (w == 7 && t > 0 && lmod == 0) {
      #pragma unroll
      for (int q = 0; q < 4; q++) {
        int row = ldiv * 4 + q;
        float lg = agl[q];
        float2 v;
        v.x = lg;
        v.y = sigm(lg);
        *reinterpret_cast<float2*>(out + ((b0 + row) * NT + (t - 1)) * 2) = v;
      }
    }

    // S2: gates, h update (args pre-scaled; no per-activation mul)
    #pragma unroll
    for (int q = 0; q < 4; q++) {
      int row = ldiv * 4 + q;
      float py = prevy_s[buf][row];
      float rv = sigm_pre(__builtin_fmaf(py, wpr, pa0[q]));
      float zv = sigm_pre(__builtin_fmaf(py, wpz, pa1[q]));
      float nv = tanh_pre(__builtin_fmaf(rv, anh[q], __builtin_fmaf(py, wpn, pa2[q])));
      float hn = __builtin_fmaf(zv, h_reg[q] - nv, nv);
      h_reg[q] = hn;
      h_bf[nbuf][row][i_own] = __float2bfloat16(hn);
    }

    // input-gate MFMAs for t+1 (uses prefetched frags; hides under barrier)
    if (t + 1 < NT) {
      pa0 = gxc[0]; pa1 = gxc[1]; pa2 = gxc[2];
      pa0 = __builtin_amdgcn_mfma_f32_16x16x32_bf16(axA_n, Bi[0][0], pa0, 0, 0, 0);
      pa1 = __builtin_amdgcn_mfma_f32_16x16x32_bf16(axA_n, Bi[1][0], pa1, 0, 0, 0);
      pa2 = __builtin_amdgcn_mfma_f32_16x16x32_bf16(axA_n, Bi[2][0], pa2, 0, 0, 0);
      pa0 = __builtin_amdgcn_mfma_f32_16x16x32_bf16(axB_n, Bi[0][1], pa0, 0, 0, 0);
      pa1 = __builtin_amdgcn_mfma_f32_16x16x32_bf16(axB_n, Bi[1][1], pa1, 0, 0, 0);
      pa2 = __builtin_amdgcn_mfma_f32_16x16x32_bf16(axB_n, Bi[2][1], pa2, 0, 0, 0);
    }

    // next-chunk convert + LDS write (rare)
    if (ck) {
      int cb2 = ((t >> 4) + 1) & 1;
      int toff = csub >> 1, c8 = (csub & 1) * 8;
      bfrag e = {f2bs(eA.x), f2bs(eA.y), f2bs(eA.z), f2bs(eA.w),
                 f2bs(eB.x), f2bs(eB.y), f2bs(eB.z), f2bs(eB.w)};
      *reinterpret_cast<bfrag*>(&eps_ch[((cb2 * 16 + toff) * 16 + cr) * 24 + c8]) = e;
      if (tid < 64) {
        int r2 = tid >> 2, s2 = tid & 3;
        *reinterpret_cast<float4*>(&y_ch[cb2 * 256 + r2 * 16 + s2 * 4]) = yv;
      }
    }

    barrier_lgkm();  // the ONE barrier per step (LDS-only drain)
  }

  // ---- tail: logit for step 255 from h_bf[0] (= H_256), direct store ----
  if (w == 7) {
    ffrag agl;
    #pragma unroll
    for (int q = 0; q < 4; q++) agl[q] = by_f;
    #pragma unroll
    for (int kc = 0; kc < 4; kc++) {
      bfrag ah = *reinterpret_cast<const bfrag*>(&h_bf[0][lmod][kc * 32 + ldiv * 8]);
      agl = __builtin_amdgcn_mfma_f32_16x16x32_bf16(ah, Bl[kc], agl, 0, 0, 0);
    }
    if (lmod == 0) {
      #pragma unroll
      for (int q = 0; q < 4; q++) {
        int row = ldiv * 4 + q;
        float lg = agl[q];
        float2 v;
        v.x = lg;
        v.y = sigm(lg);
        *reinterpret_cast<float2*>(out + ((b0 + row) * NT + 255) * 2) = v;
      }
    }
  }
}

extern "C" void kernel_launch(void* const* d_in, const int* in_sizes, int n_in,
                              void* d_out, int out_size, void* d_ws, size_t ws_size,
                              hipStream_t stream) {
  const float* x   = (const float*)d_in[0];
  const int*   a   = (const int*)d_in[1];
  const int*   tt  = (const int*)d_in[2];
  const float* y   = (const float*)d_in[3];
  // d_in[4] = mask: forward output is mask-independent (m*v + (1-m)*v == v)
  const float* eps = (const float*)d_in[5];
  const float* Wx  = (const float*)d_in[6];
  const float* bx  = (const float*)d_in[7];
  const float* Ea  = (const float*)d_in[8];
  const float* Et  = (const float*)d_in[9];
  const float* Wih = (const float*)d_in[10];
  const float* Whh = (const float*)d_in[11];
  const float* bih = (const float*)d_in[12];
  const float* bhh = (const float*)d_in[13];
  const float* W0  = (const float*)d_in[14];
  const float* b0  = (const float*)d_in[15];
  const float* Wy  = (const float*)d_in[16];
  const float* by  = (const float*)d_in[17];
  float* out = (float*)d_out;

  gru_kernel<<<NB / 16, 512, 0, stream>>>(x, a, tt, y, eps, Wx, bx, Ea, Et,
                                          Wih, Whh, bih, bhh, W0, b0, Wy, by, out);
}

// Round 8
// 347.281 us; speedup vs baseline: 1.0467x; 1.0467x over previous
//
#include <hip/hip_runtime.h>
#include <hip/hip_bf16.h>

typedef __attribute__((ext_vector_type(8))) short bfrag;   // 8 x bf16 (4 VGPRs)
typedef __attribute__((ext_vector_type(4))) float ffrag;   // 4 x f32 acc

#define NB 1024
#define NT 256

// -log2(e), -2*log2(e): folded into weights so S2 needs no per-activation mul.
#define KSIG -1.44269504f
#define KTAN -2.88539008f

static __device__ __forceinline__ float fast_rcp(float x) { return __builtin_amdgcn_rcpf(x); }
// unscaled (logit path only)
static __device__ __forceinline__ float sigm(float x) {
  return fast_rcp(1.f + __builtin_amdgcn_exp2f(-1.44269504f * x));
}
// pre-scaled args (weights already multiplied by KSIG/KTAN)
static __device__ __forceinline__ float sigm_pre(float s) {
  return fast_rcp(1.f + __builtin_amdgcn_exp2f(s));
}
static __device__ __forceinline__ float tanh_pre(float s) {
  return __builtin_fmaf(2.f, fast_rcp(1.f + __builtin_amdgcn_exp2f(s)), -1.f);
}
static __device__ __forceinline__ float tanh_f(float x) {
  return __builtin_fmaf(2.f, fast_rcp(1.f + __builtin_amdgcn_exp2f(-2.88539008f * x)), -1.f);
}
static __device__ __forceinline__ float bf2f(__hip_bfloat16 v) { return __bfloat162float(v); }
static __device__ __forceinline__ short f2bs(float f) {
  __hip_bfloat16 h = __float2bfloat16(f);
  return *reinterpret_cast<short*>(&h);
}
// LDS-only barrier: skip the vmcnt(0) drain __syncthreads would force.
static __device__ __forceinline__ void barrier_lgkm() {
  asm volatile("s_waitcnt lgkmcnt(0)\n\ts_barrier" ::: "memory");
}

// ---------------------------------------------------------------------------
// R19 = R18 RESUBMIT (Round 7 was an infra failure: "MI355X container failed
// twice" — kernel never ran). No source changes.
// R18 = R12 (verified 265us kernel) + ONE delta: direct float2 global stores
// for the logit/prob output (out_b slot buffer + flush subsystem deleted).
// R17's other two deltas REVERTED (evidence: R17 = R12+3 deltas regressed
// 265->275us):
//  - input-gather hoist: moving the dyn ds_reads before the h-MFMAs made
//    their lgkm waits interleave with the h A-frag reads on the post-barrier
//    critical path. R12's tail placement restored.
//  - setprio: NULL on barrier-lockstep structures (T5 needs role-split).
// Grid-256/4-row family stays ABANDONED: 4 identical failures (absmax
// 0.6953125 consistent with an unwritten output), five clean audits, cause
// not statically findable; per-CU VALU can only drop via lane compaction,
// which is exactly the failing family.
// ---------------------------------------------------------------------------
__global__ __launch_bounds__(512, 2) void gru_kernel(
    const float* __restrict__ x,     // [B,64]
    const int* __restrict__ a_ids,   // [B,T]
    const int* __restrict__ t_ids,   // [B,T]
    const float* __restrict__ y,     // [B,T]
    const float* __restrict__ eps,   // [B,T,16]
    const float* __restrict__ Wx,    // [64,64]
    const float* __restrict__ bx,    // [64]
    const float* __restrict__ Ea,    // [100,32]
    const float* __restrict__ Et,    // [4,16]
    const float* __restrict__ Wih,   // [384,129]
    const float* __restrict__ Whh,   // [384,128]
    const float* __restrict__ bih,   // [384]
    const float* __restrict__ bhh,   // [384]
    const float* __restrict__ W0,    // [128,80]
    const float* __restrict__ b0g,   // [128]
    const float* __restrict__ Wy,    // [1,128]
    const float* __restrict__ by,    // [1]
    float* __restrict__ out)         // [B,T,2]
{
  // ---- persistent LDS ----
  __shared__ __align__(16) __hip_bfloat16 h_bf[2][16][136];  // h mirror (h_bf[1] = xdyn in prologue)
  __shared__ __align__(16) __hip_bfloat16 Ea_s[100][40];     // padded rows (data in cols 0..31)
  __shared__ __align__(16) __hip_bfloat16 Et_s[4][16];
  __shared__ float prevy_s[2][16];
  __shared__ float bsum_r[128], bsum_z[128], bihn_s[128], bhhn_s[128];  // pre-scaled
  __shared__ float wprev_s[384];                                        // pre-scaled
  // ---- unioned region (38912 B) ----
  // persistent: id_s[256][16]u16 @0 | eps_ch[2][16][16][24]bf16 @8192
  //             y_ch[2][16][16]f32 @32768
  // prologue:   Wxb[64][64]bf16 @0 | W0b[128][80]bf16 @8192 | x_s[16][65]f32 @28672
  //             eps0s[16][17]f32 @32832 | xe_s[16][65]f32 @33920 | h0f[16][128]f32 @0
  __shared__ __align__(16) char uni[38912];
  unsigned short* id_s    = (unsigned short*)(uni);
  __hip_bfloat16* eps_ch  = (__hip_bfloat16*)(uni + 8192);
  float*          y_ch    = (float*)(uni + 32768);
  __hip_bfloat16* Wxb     = (__hip_bfloat16*)(uni);
  __hip_bfloat16* W0b     = (__hip_bfloat16*)(uni + 8192);
  float*          x_s     = (float*)(uni + 28672);
  float*          eps0s   = (float*)(uni + 32832);
  float*          xe_s    = (float*)(uni + 33920);
  float*          h0f     = (float*)(uni);

  const int tid = threadIdx.x;
  const int w = tid >> 6, l = tid & 63;
  const int lmod = l & 15, ldiv = l >> 4;
  const int i_own = 16 * w + lmod;
  const int b0 = blockIdx.x * 16;

  // ================= PROLOGUE =================
  if (tid < 128) {
    bsum_r[tid] = KSIG * (bih[tid] + bhh[tid]);
    bsum_z[tid] = KSIG * (bih[128 + tid] + bhh[128 + tid]);
    bihn_s[tid] = KTAN * bih[256 + tid];
    bhhn_s[tid] = KTAN * bhh[256 + tid];
  }
  if (tid < 384) wprev_s[tid] = ((tid < 256) ? KSIG : KTAN) * Wih[tid * 129 + 128];
  for (int j = tid; j < 3200; j += 512) {
    int r = j >> 5, c = j & 31;
    Ea_s[r][c] = __float2bfloat16(Ea[j]);
  }
  if (tid < 64) ((__hip_bfloat16*)Et_s)[tid] = __float2bfloat16(Et[tid]);
  for (int j = tid; j < 4096; j += 512)  Wxb[j] = __float2bfloat16(Wx[j]);
  for (int j = tid; j < 10240; j += 512) W0b[j] = __float2bfloat16(W0[j]);
  for (int j = tid; j < 1024; j += 512) {
    int r = j >> 6, c = j & 63;
    x_s[r * 65 + c] = x[(b0 + r) * 64 + c];
  }
  if (tid < 256) {
    int r = tid >> 4, c = tid & 15;
    eps0s[r * 17 + c] = eps[((b0 + r) * NT) * 16 + c];
  }
  const float by_f = by[0];

  // persistent B-frags: wave w owns gate-cols i_own of r/z/n. Pre-scaled.
  bfrag Bh[3][4], Bi[3][2];
  #pragma unroll
  for (int g = 0; g < 3; g++) {
    const float sg = (g < 2) ? KSIG : KTAN;
    int n = (g * 8 + w) * 16 + lmod;
    #pragma unroll
    for (int kc = 0; kc < 4; kc++) {
      int k = kc * 32 + ldiv * 8;
      const float* wh = Whh + n * 128 + k;
      float4 h0v = *reinterpret_cast<const float4*>(wh);
      float4 h1v = *reinterpret_cast<const float4*>(wh + 4);
      bfrag th = {f2bs(sg * h0v.x), f2bs(sg * h0v.y), f2bs(sg * h0v.z), f2bs(sg * h0v.w),
                  f2bs(sg * h1v.x), f2bs(sg * h1v.y), f2bs(sg * h1v.z), f2bs(sg * h1v.w)};
      Bh[g][kc] = th;
    }
    #pragma unroll
    for (int kc = 0; kc < 2; kc++) {
      bfrag ti;
      #pragma unroll
      for (int j = 0; j < 8; j++) {
        int dk = kc * 32 + ldiv * 8 + j;
        int col = dk < 48 ? dk : dk + 64;
        ti[j] = f2bs(sg * Wih[n * 129 + col]);
      }
      Bi[g][kc] = ti;
    }
  }
  // logit B-tile for wave 7: col 0 = Wy, other cols 0 (UNscaled)
  bfrag Bl[4];
  if (w == 7) {
    #pragma unroll
    for (int kc = 0; kc < 4; kc++) {
      bfrag bt;
      #pragma unroll
      for (int j = 0; j < 8; j++)
        bt[j] = (lmod == 0) ? f2bs(Wy[kc * 32 + ldiv * 8 + j]) : (short)0;
      Bl[kc] = bt;
    }
  }
  __syncthreads();  // B1: x_s, Wxb, tables ready

  // ph1: xenc = x@Wx.T + bx -> xe_s (f32) + xdyn bf16 (in h_bf[1])
  for (int j = tid; j < 1024; j += 512) {
    int r = j & 15, i = j >> 4;
    float acc = bx[i];
    #pragma unroll 8
    for (int k = 0; k < 64; k++) acc += x_s[r * 65 + k] * bf2f(Wxb[i * 64 + k]);
    xe_s[r * 65 + i] = acc;
    h_bf[1][r][i] = __float2bfloat16(acc);
  }
  __syncthreads();  // B2: xe_s + xdyn ready; Wxb dead

  // ph2: h0 = tanh([xenc,eps0]@W0.T + b0) -> h0f (overwrites Wxb region)
  for (int j = tid; j < 2048; j += 512) {
    int r = j & 15, o = j >> 4;
    float acc = b0g[o];
    #pragma unroll 8
    for (int k = 0; k < 64; k++) acc += xe_s[r * 65 + k] * bf2f(W0b[o * 80 + k]);
    #pragma unroll
    for (int k = 0; k < 16; k++) acc += eps0s[r * 17 + k] * bf2f(W0b[o * 80 + 64 + k]);
    h0f[r * 128 + o] = tanh_f(acc);
  }

  // gxc = scaled( xenc @ Wih[:,48:112].T + per-gate biases )
  ffrag gxc[3];
  {
    ffrag z = {0.f, 0.f, 0.f, 0.f};
    gxc[0] = z; gxc[1] = z; gxc[2] = z;
    #pragma unroll
    for (int kc = 0; kc < 2; kc++) {
      bfrag axd = *reinterpret_cast<const bfrag*>(&h_bf[1][lmod][kc * 32 + ldiv * 8]);
      #pragma unroll
      for (int g = 0; g < 3; g++) {
        const float sg = (g < 2) ? KSIG : KTAN;
        int n = (g * 8 + w) * 16 + lmod;
        const float* wi = Wih + n * 129 + 48 + kc * 32 + ldiv * 8;
        bfrag bt;
        #pragma unroll
        for (int j = 0; j < 8; j++) bt[j] = f2bs(sg * wi[j]);
        gxc[g] = __builtin_amdgcn_mfma_f32_16x16x32_bf16(axd, bt, gxc[g], 0, 0, 0);
      }
    }
    float brf = bsum_r[i_own], bzf = bsum_z[i_own], bn1 = bihn_s[i_own];
    #pragma unroll
    for (int q = 0; q < 4; q++) {
      gxc[0][q] += brf;
      gxc[1][q] += bzf;
      gxc[2][q] += bn1;
    }
  }
  __syncthreads();  // B3: h0f complete; gxc done

  // h init: fp32 regs + bf16 mirror in h_bf[0]
  float h_reg[4];
  #pragma unroll
  for (int q = 0; q < 4; q++) {
    int row = ldiv * 4 + q;
    float hv = h0f[row * 128 + i_own];
    h_reg[q] = hv;
    h_bf[0][row][i_own] = __float2bfloat16(hv);
  }
  __syncthreads();  // B4: h0f dead; uni becomes persistent

  // ids (packed, [t][row]) + chunk 0 of eps/y
  for (int j = tid; j < 4096; j += 512) {
    int r = j >> 8, t = j & 255;
    unsigned short v = (unsigned short)(a_ids[(b0 + r) * NT + t] |
                                        (t_ids[(b0 + r) * NT + t] << 8));
    id_s[t * 16 + r] = v;
  }
  {
    int r = tid >> 5, sub = tid & 31;
    const float* p = eps + ((b0 + r) * NT) * 16 + sub * 8;
    float4 eA = *reinterpret_cast<const float4*>(p);
    float4 eB = *reinterpret_cast<const float4*>(p + 4);
    int toff = sub >> 1, c8 = (sub & 1) * 8;
    bfrag e = {f2bs(eA.x), f2bs(eA.y), f2bs(eA.z), f2bs(eA.w),
               f2bs(eB.x), f2bs(eB.y), f2bs(eB.z), f2bs(eB.w)};
    *reinterpret_cast<bfrag*>(&eps_ch[(toff * 16 + r) * 24 + c8]) = e;
    if (tid < 64) {
      int r2 = tid >> 2, s2 = tid & 3;
      float4 yv = *reinterpret_cast<const float4*>(y + (b0 + r2) * NT + s2 * 4);
      *reinterpret_cast<float4*>(&y_ch[r2 * 16 + s2 * 4]) = yv;
    }
  }
  if (tid < 16) prevy_s[0][tid] = 0.f;
  // hoisted per-lane constants (pre-scaled)
  const float wpr = wprev_s[i_own], wpz = wprev_s[128 + i_own], wpn = wprev_s[256 + i_own];
  const float bn2 = bhhn_s[i_own];
  // hoisted per-lane address pieces for the direct dyn-input gather
  const char* const ea_base  = (const char*)Ea_s + ldiv * 16;
  const char* const et_base  = (const char*)Et_s + ldiv * 16;
  const char* const eps_base = (const char*)eps_ch + lmod * 48 + (ldiv - 2) * 16;
  __syncthreads();  // B5: id_s / eps_ch chunk0 / y_ch ready

  // input-gate MFMAs for t=0
  ffrag pa0 = gxc[0], pa1 = gxc[1], pa2 = gxc[2];
  {
    int id = id_s[lmod];
    int aid = id & 127, tv = id >> 8;
    bfrag axA = *reinterpret_cast<const bfrag*>(ea_base + aid * 80);
    const char* etp = et_base + tv * 32;
    const char* epp = eps_base;  // t=0: cbn=0, tm=0
    bfrag axB = *reinterpret_cast<const bfrag*>(ldiv < 2 ? etp : epp);
    pa0 = __builtin_amdgcn_mfma_f32_16x16x32_bf16(axA, Bi[0][0], pa0, 0, 0, 0);
    pa1 = __builtin_amdgcn_mfma_f32_16x16x32_bf16(axA, Bi[1][0], pa1, 0, 0, 0);
    pa2 = __builtin_amdgcn_mfma_f32_16x16x32_bf16(axA, Bi[2][0], pa2, 0, 0, 0);
    pa0 = __builtin_amdgcn_mfma_f32_16x16x32_bf16(axB, Bi[0][1], pa0, 0, 0, 0);
    pa1 = __builtin_amdgcn_mfma_f32_16x16x32_bf16(axB, Bi[1][1], pa1, 0, 0, 0);
    pa2 = __builtin_amdgcn_mfma_f32_16x16x32_bf16(axB, Bi[2][1], pa2, 0, 0, 0);
  }

  // ================= MAIN LOOP =================
  for (int t = 0; t < NT; t++) {
    const int buf = t & 1, nbuf = buf ^ 1;

    // issue next-chunk global loads (rare)
    const bool ck = ((t & 15) == 0) && (t + 16 < NT);
    float4 eA, eB, yv;
    const int cr = tid >> 5, csub = tid & 31;
    if (ck) {
      const float* p = eps + ((b0 + cr) * NT + t + 16) * 16 + csub * 8;
      eA = *reinterpret_cast<const float4*>(p);
      eB = *reinterpret_cast<const float4*>(p + 4);
      if (tid < 64) {
        int r2 = tid >> 2, s2 = tid & 3;
        yv = *reinterpret_cast<const float4*>(y + (b0 + r2) * NT + t + 16 + s2 * 4);
      }
    }

    // h-MFMAs: the only barrier-dependent work
    ffrag anh, agl;
    #pragma unroll
    for (int q = 0; q < 4; q++) anh[q] = bn2;
    if (w == 7) {
      #pragma unroll
      for (int q = 0; q < 4; q++) agl[q] = by_f;
    }
    #pragma unroll
    for (int kc = 0; kc < 4; kc++) {
      bfrag ah = *reinterpret_cast<const bfrag*>(&h_bf[buf][lmod][kc * 32 + ldiv * 8]);
      pa0 = __builtin_amdgcn_mfma_f32_16x16x32_bf16(ah, Bh[0][kc], pa0, 0, 0, 0);
      pa1 = __builtin_amdgcn_mfma_f32_16x16x32_bf16(ah, Bh[1][kc], pa1, 0, 0, 0);
      anh = __builtin_amdgcn_mfma_f32_16x16x32_bf16(ah, Bh[2][kc], anh, 0, 0, 0);
      if (w == 7)
        agl = __builtin_amdgcn_mfma_f32_16x16x32_bf16(ah, Bl[kc], agl, 0, 0, 0);
    }

    // prevy for t+1 (wave 6)
    if (tid >= 384 && tid < 400) {
      int r = tid - 384;
      prevy_s[nbuf][r] = y_ch[((t >> 4) & 1) * 256 + r * 16 + (t & 15)];
    }

    // wave 7: logit/prob for step t-1 -> DIRECT global float2 stores
    if (w == 7 && t > 0 && lmod == 0) {
      #pragma unroll
      for (int q = 0; q < 4; q++) {
        int row = ldiv * 4 + q;
        float lg = agl[q];
        float2 v;
        v.x = lg;
        v.y = sigm(lg);
        *reinterpret_cast<float2*>(out + ((b0 + row) * NT + (t - 1)) * 2) = v;
      }
    }

    // S2: gates, h update (args pre-scaled; no per-activation mul)
    #pragma unroll
    for (int q = 0; q < 4; q++) {
      int row = ldiv * 4 + q;
      float py = prevy_s[buf][row];
      float rv = sigm_pre(__builtin_fmaf(py, wpr, pa0[q]));
      float zv = sigm_pre(__builtin_fmaf(py, wpz, pa1[q]));
      float nv = tanh_pre(__builtin_fmaf(rv, anh[q], __builtin_fmaf(py, wpn, pa2[q])));
      float hn = __builtin_fmaf(zv, h_reg[q] - nv, nv);
      h_reg[q] = hn;
      h_bf[nbuf][row][i_own] = __float2bfloat16(hn);
    }

    // input-gate MFMAs for t+1 (independent of h_t; hides under barrier)
    if (t + 1 < NT) {
      const int tn = t + 1;
      const int ebase = (((tn >> 4) & 1) * 16 + (tn & 15)) * 16;  // eps row-block
      int id = id_s[tn * 16 + lmod];
      int aid = id & 127, tv = id >> 8;
      bfrag axA = *reinterpret_cast<const bfrag*>(ea_base + aid * 80);
      const char* etp = et_base + tv * 32;
      const char* epp = eps_base + ebase * 48;
      bfrag axB = *reinterpret_cast<const bfrag*>(ldiv < 2 ? etp : epp);
      pa0 = gxc[0]; pa1 = gxc[1]; pa2 = gxc[2];
      pa0 = __builtin_amdgcn_mfma_f32_16x16x32_bf16(axA, Bi[0][0], pa0, 0, 0, 0);
      pa1 = __builtin_amdgcn_mfma_f32_16x16x32_bf16(axA, Bi[1][0], pa1, 0, 0, 0);
      pa2 = __builtin_amdgcn_mfma_f32_16x16x32_bf16(axA, Bi[2][0], pa2, 0, 0, 0);
      pa0 = __builtin_amdgcn_mfma_f32_16x16x32_bf16(axB, Bi[0][1], pa0, 0, 0, 0);
      pa1 = __builtin_amdgcn_mfma_f32_16x16x32_bf16(axB, Bi[1][1], pa1, 0, 0, 0);
      pa2 = __builtin_amdgcn_mfma_f32_16x16x32_bf16(axB, Bi[2][1], pa2, 0, 0, 0);
    }

    // next-chunk convert + LDS write (rare)
    if (ck) {
      int cb2 = ((t >> 4) + 1) & 1;
      int toff = csub >> 1, c8 = (csub & 1) * 8;
      bfrag e = {f2bs(eA.x), f2bs(eA.y), f2bs(eA.z), f2bs(eA.w),
                 f2bs(eB.x), f2bs(eB.y), f2bs(eB.z), f2bs(eB.w)};
      *reinterpret_cast<bfrag*>(&eps_ch[((cb2 * 16 + toff) * 16 + cr) * 24 + c8]) = e;
      if (tid < 64) {
        int r2 = tid >> 2, s2 = tid & 3;
        *reinterpret_cast<float4*>(&y_ch[cb2 * 256 + r2 * 16 + s2 * 4]) = yv;
      }
    }

    barrier_lgkm();  // the ONE barrier per step (LDS-only drain)
  }

  // ---- tail: logit for step 255 from h_bf[0] (= H_256), direct store ----
  if (w == 7) {
    ffrag agl;
    #pragma unroll
    for (int q = 0; q < 4; q++) agl[q] = by_f;
    #pragma unroll
    for (int kc = 0; kc < 4; kc++) {
      bfrag ah = *reinterpret_cast<const bfrag*>(&h_bf[0][lmod][kc * 32 + ldiv * 8]);
      agl = __builtin_amdgcn_mfma_f32_16x16x32_bf16(ah, Bl[kc], agl, 0, 0, 0);
    }
    if (lmod == 0) {
      #pragma unroll
      for (int q = 0; q < 4; q++) {
        int row = ldiv * 4 + q;
        float lg = agl[q];
        float2 v;
        v.x = lg;
        v.y = sigm(lg);
        *reinterpret_cast<float2*>(out + ((b0 + row) * NT + 255) * 2) = v;
      }
    }
  }
}

extern "C" void kernel_launch(void* const* d_in, const int* in_sizes, int n_in,
                              void* d_out, int out_size, void* d_ws, size_t ws_size,
                              hipStream_t stream) {
  const float* x   = (const float*)d_in[0];
  const int*   a   = (const int*)d_in[1];
  const int*   tt  = (const int*)d_in[2];
  const float* y   = (const float*)d_in[3];
  // d_in[4] = mask: forward output is mask-independent (m*v + (1-m)*v == v)
  const float* eps = (const float*)d_in[5];
  const float* Wx  = (const float*)d_in[6];
  const float* bx  = (const float*)d_in[7];
  const float* Ea  = (const float*)d_in[8];
  const float* Et  = (const float*)d_in[9];
  const float* Wih = (const float*)d_in[10];
  const float* Whh = (const float*)d_in[11];
  const float* bih = (const float*)d_in[12];
  const float* bhh = (const float*)d_in[13];
  const float* W0  = (const float*)d_in[14];
  const float* b0  = (const float*)d_in[15];
  const float* Wy  = (const float*)d_in[16];
  const float* by  = (const float*)d_in[17];
  float* out = (float*)d_out;

  gru_kernel<<<NB / 16, 512, 0, stream>>>(x, a, tt, y, eps, Wx, bx, Ea, Et,
                                          Wih, Whh, bih, bhh, W0, b0, Wy, by, out);
}